// Round 6
// baseline (428.428 us; speedup 1.0000x reference)
//
#include <hip/hip_runtime.h>
#include <hip/hip_cooperative_groups.h>

namespace cg = cooperative_groups;

// MorphoMLP: y = relu(maxplus(relu(maxplus(x,W1)), W2)), fp32.
// B=512, IN=512, HID=1024, OUT=512.
// R8: single cooperative kernel. R2/R5/R6/R7 tied ~95-109us across every
//     intra-kernel knob (occupancy, instr/update, barriers, traffic) while
//     the pipe model says morphos cost <=10us each -> the invariant is the
//     INTER-KERNEL structure: launch gaps + per-boundary L2 writeback/inv
//     (non-coherent per-XCD L2s) + cold-L2 restart of staging reads.
//     Fix: fuse transpose -> M1 -> M2 -> combine into ONE cooperative launch
//     with grid.sync() between phases; partials stay warm in L2.
//   - Morpho internals verbatim from R6 (94.9us, absmax 0): 64x64x(2x64)
//     tiles, 4x4 frag, pk_add f32x2 + v_max3, ZFOLD combine-fusion in M2.
//   - 512 blocks x 256 thr, 32KB LDS, 2 blocks/CU co-resident.
// ws: xT 1MB | W1T 2MB | W2T 2MB | hp 8MB | yp 8MB = 21MB

#define WS_XT   0                           // [512][512]    x^T  [k][b]
#define WS_W1T  (512 * 512)                 // [512][1024]   W1^T [k][j]
#define WS_W2T  (WS_W1T + 512 * 1024)       // [1024][512]   W2^T [k2][o]
#define WS_HP   (WS_W2T + 1024 * 512)       // [4][1024][512]  L1 partials [z][j][b]
#define WS_YP   (WS_HP + 4 * 1024 * 512)    // [8][512][512]   L2 partials [z][b][o]

typedef float f32x2 __attribute__((ext_vector_type(2)));

__device__ __forceinline__ float4 fmax4(float4 a, float4 b) {
    return make_float4(fmaxf(a.x, b.x), fmaxf(a.y, b.y),
                       fmaxf(a.z, b.z), fmaxf(a.w, b.w));
}

// ---------------------------------------------------------------------------
// One 32x32 transpose tile-unit (id in [0,1280)): x->xT, W1->W1T, W2->W2T.
__device__ void transposeUnit(int id, const float* __restrict__ x,
                              const float* __restrict__ W1,
                              const float* __restrict__ W2,
                              float* __restrict__ ws, int t, float* lbuf) {
    float (*tt)[33] = (float(*)[33])lbuf;        // 4224B of lA
    const float* src;
    float* dst;
    int R, C, rt, ct;
    if (id < 256) {
        src = x;  dst = ws + WS_XT;  R = 512;  C = 512;
        rt = id >> 4;          ct = id & 15;
    } else if (id < 768) {
        int b = id - 256;
        src = W1; dst = ws + WS_W1T; R = 1024; C = 512;
        rt = b >> 4;           ct = b & 15;
    } else {
        int b = id - 768;
        src = W2; dst = ws + WS_W2T; R = 512;  C = 1024;
        rt = b >> 5;           ct = b & 31;
    }
    const int tx = t & 31, ty = t >> 5;
    const int r0 = rt * 32, c0 = ct * 32;
#pragma unroll
    for (int r = 0; r < 4; r++)
        tt[ty + 8 * r][tx] = src[(size_t)(r0 + ty + 8 * r) * C + c0 + tx];
    __syncthreads();
#pragma unroll
    for (int r = 0; r < 4; r++)
        dst[(size_t)(c0 + ty + 8 * r) * R + r0 + tx] = tt[tx][ty + 8 * r];
    __syncthreads();                             // WAR before next unit/phase
}

// ---------------------------------------------------------------------------
// R6 morpho7 body, verbatim, as a device function on virtual block (bx,by,bz).
// A-role: [K][512] K-major; W-role: [K][JDIM] K-major.
// 64j x 64b x KPER k (chunks of 64), 4j x 4b frag/thread, acc init 0 = relu.
// ZFOLD>1: W staging maxes ZFOLD slices (stride WSLICE f4) + relu (fused
// combine of the previous layer). Stores partial P[bz][j][b], f4 over b.
template <int JDIM, int KPER, int ZFOLD, int WSLICE>
__device__ void morphoBody(const float* __restrict__ A,
                           const float* __restrict__ W,
                           float* __restrict__ P,
                           int bx, int by, int bz, int t,
                           float* __restrict__ lA, float* __restrict__ lW) {
    const int tx = t & 15;           // b frag: b0 + tx*4 + {0..3}
    const int ty = t >> 4;           // j frag: j0 + ty*4 + {0..3}
    const int j0 = bx * 64;
    const int b0 = by * 64;
    const int k0 = bz * KPER;

    float acc[4][4];                 // [j][b], init 0 == relu fold
#pragma unroll
    for (int jj = 0; jj < 4; jj++)
#pragma unroll
        for (int i = 0; i < 4; i++) acc[jj][i] = 0.0f;

    const float4* lA4 = (const float4*)lA;
    const float4* lW4 = (const float4*)lW;

    for (int ks = 0; ks < KPER; ks += 64) {
        if (ks) __syncthreads();     // WAR: all waves done reading prev tiles

        // ---- stage tiles: 1024 float4 each, 4/thread, coalesced ----
        const float4* A4 = (const float4*)(A + (size_t)(k0 + ks) * 512) + (b0 >> 2);
        const float4* W4 = (const float4*)(W + (size_t)(k0 + ks) * JDIM) + (j0 >> 2);
#pragma unroll
        for (int r = 0; r < 4; r++) {
            const int q   = t + 256 * r;
            const int row = q >> 4, col = q & 15;   // 16 f4 per 64-float row
            ((float4*)lA)[q] = A4[(size_t)row * 128 + col];
            const size_t woff = (size_t)row * (JDIM / 4) + col;
            float4 w = W4[woff];
            if (ZFOLD > 1) {
#pragma unroll
                for (int z = 1; z < ZFOLD; z++)
                    w = fmax4(w, W4[woff + (size_t)z * WSLICE]);
                w = fmax4(w, make_float4(0.f, 0.f, 0.f, 0.f));   // relu
            }
            ((float4*)lW)[q] = w;
        }
        __syncthreads();

        // ---- inner max-plus: 2 k's/iter; pk adds (f32x2) + v_max3 merges ----
#pragma unroll 8
        for (int kk = 0; kk < 64; kk += 2) {
            const float4 a0 = lA4[kk * 16 + tx];         // k,   b frag
            const float4 a1 = lA4[kk * 16 + 16 + tx];    // k+1, b frag
            const float4 w0 = lW4[kk * 16 + ty];         // k,   j frag
            const float4 w1 = lW4[kk * 16 + 16 + ty];    // k+1, j frag

            const f32x2 a0p0 = {a0.x, a0.y}, a0p1 = {a0.z, a0.w};
            const f32x2 a1p0 = {a1.x, a1.y}, a1p1 = {a1.z, a1.w};

#define UPDJ(JR, W0, W1)                                                    \
    {                                                                       \
        const f32x2 wa = {(W0), (W0)};                                      \
        const f32x2 wb = {(W1), (W1)};                                      \
        const f32x2 s0 = a0p0 + wa, t0 = a1p0 + wb;                         \
        const f32x2 s1 = a0p1 + wa, t1 = a1p1 + wb;                         \
        acc[JR][0] = fmaxf(fmaxf(acc[JR][0], s0.x), t0.x);                  \
        acc[JR][1] = fmaxf(fmaxf(acc[JR][1], s0.y), t0.y);                  \
        acc[JR][2] = fmaxf(fmaxf(acc[JR][2], s1.x), t1.x);                  \
        acc[JR][3] = fmaxf(fmaxf(acc[JR][3], s1.y), t1.y);                  \
    }
            UPDJ(0, w0.x, w1.x)
            UPDJ(1, w0.y, w1.y)
            UPDJ(2, w0.z, w1.z)
            UPDJ(3, w0.w, w1.w)
#undef UPDJ
        }
    }

    // ---- store partial: P[bz][j][b], float4 over b (coalesced) ----
    float* Pp = P + (size_t)bz * JDIM * 512;
#pragma unroll
    for (int jj = 0; jj < 4; jj++) {
        const float4 v = make_float4(acc[jj][0], acc[jj][1], acc[jj][2], acc[jj][3]);
        *(float4*)(Pp + (size_t)(j0 + ty * 4 + jj) * 512 + b0 + tx * 4) = v;
    }
}

// ---------------------------------------------------------------------------
// The whole pipeline in one cooperative kernel. 512 blocks x 256 threads.
__global__ __launch_bounds__(256, 2) void fusedAll(const float* __restrict__ x,
                                                   const float* __restrict__ W1,
                                                   const float* __restrict__ W2,
                                                   float* __restrict__ ws,
                                                   float* __restrict__ out) {
    __shared__ float lA[64 * 64];    // 16KB
    __shared__ float lW[64 * 64];    // 16KB
    cg::grid_group grid = cg::this_grid();
    const int bid = blockIdx.x;
    const int t   = threadIdx.x;

    // ---- phase 0: transposes (1280 units over 512 blocks) ----
    for (int u = bid; u < 1280; u += 512)
        transposeUnit(u, x, W1, W2, ws, t, lA);
    __threadfence();
    grid.sync();

    // ---- phase 1: L1 morpho. virtual grid 16(j) x 8(b) x 4(z), KPER=128 ----
    morphoBody<1024, 128, 1, 1>(ws + WS_XT, ws + WS_W1T, ws + WS_HP,
                                bid & 15, (bid >> 4) & 7, bid >> 7, t, lA, lW);
    __threadfence();
    grid.sync();

    // ---- phase 2: L2 morpho, role-swapped (W-role = hp with ZFOLD=4 fused
    //      combineH+relu; A-role = W2T). virtual grid 8(b) x 8(o) x 8(z).
    //      Output yp[z][b][o]. hp slice stride = 1024*512/4 = 131072 f4. ----
    morphoBody<512, 128, 4, 131072>(ws + WS_W2T, ws + WS_HP, ws + WS_YP,
                                    bid & 7, (bid >> 3) & 7, bid >> 6, t, lA, lW);
    __threadfence();
    grid.sync();

    // ---- phase 3: combine 8 yp slices -> out[b][o] (pre-relu'd, no transpose)
    if (bid < 256) {
        const int i = bid * 256 + t;             // float4 index over 256K floats
        const float4* p = (const float4*)(ws + WS_YP);
        float4 m = p[i];
#pragma unroll
        for (int z = 1; z < 8; z++) m = fmax4(m, p[i + z * 65536]);
        ((float4*)out)[i] = m;
    }
}

// ---------------------------------------------------------------------------
extern "C" void kernel_launch(void* const* d_in, const int* in_sizes, int n_in,
                              void* d_out, int out_size, void* d_ws, size_t ws_size,
                              hipStream_t stream) {
    (void)in_sizes; (void)n_in; (void)out_size; (void)ws_size;
    const float* x  = (const float*)d_in[0];
    const float* W1 = (const float*)d_in[1];
    const float* W2 = (const float*)d_in[2];
    float* ws  = (float*)d_ws;
    float* out = (float*)d_out;

    void* args[] = {(void*)&x, (void*)&W1, (void*)&W2, (void*)&ws, (void*)&out};
    hipLaunchCooperativeKernel((const void*)fusedAll, dim3(512), dim3(256),
                               args, 0, stream);
}

// Round 7
// 192.816 us; speedup vs baseline: 2.2219x; 2.2219x over previous
//
#include <hip/hip_runtime.h>

// MorphoMLP: y = relu(maxplus(relu(maxplus(x,W1)), W2)), fp32.
// B=512, IN=512, HID=1024, OUT=512.
// R9: MEASUREMENT ROUND. R6 pipeline verbatim (94.9us best), but both morpho
//     bodies repeat their full staged k-loop MREP=6 times. max is idempotent
//     over identical data -> bit-identical output, ~6x dilation of the morpho
//     dispatches so they out-rank the harness's 43us fill kernels in the
//     rocprof top-5 and we finally see their VALUBusy / LDS-conflict /
//     FETCH / occupancy. Six structural theories are dead; buy data.
// ws: xT 1MB | W1T 2MB | W2T 2MB | hp 8MB | yp 8MB = 21MB

#define MREP 6

#define WS_XT   0                           // [512][512]    x^T  [k][b]
#define WS_W1T  (512 * 512)                 // [512][1024]   W1^T [k][j]
#define WS_W2T  (WS_W1T + 512 * 1024)       // [1024][512]   W2^T [k2][o]
#define WS_HP   (WS_W2T + 1024 * 512)       // [4][1024][512]  L1 partials [z][j][b]
#define WS_YP   (WS_HP + 4 * 1024 * 512)    // [8][512][512]   L2 partials [z][b][o]

typedef float f32x2 __attribute__((ext_vector_type(2)));

__device__ __forceinline__ float4 fmax4(float4 a, float4 b) {
    return make_float4(fmaxf(a.x, b.x), fmaxf(a.y, b.y),
                       fmaxf(a.z, b.z), fmaxf(a.w, b.w));
}

// ---------------------------------------------------------------------------
// Fused transpose of x (512x512), W1 (1024x512), W2 (512x1024) into ws.
__global__ __launch_bounds__(256) void transpose3(const float* __restrict__ x,
                                                  const float* __restrict__ W1,
                                                  const float* __restrict__ W2,
                                                  float* __restrict__ ws) {
    __shared__ float t[32][33];
    const int id = blockIdx.x;
    const float* src;
    float* dst;
    int R, C, rt, ct;
    if (id < 256) {
        src = x;  dst = ws + WS_XT;  R = 512;  C = 512;
        rt = id >> 4;          ct = id & 15;
    } else if (id < 768) {
        int b = id - 256;
        src = W1; dst = ws + WS_W1T; R = 1024; C = 512;
        rt = b >> 4;           ct = b & 15;
    } else {
        int b = id - 768;
        src = W2; dst = ws + WS_W2T; R = 512;  C = 1024;
        rt = b >> 5;           ct = b & 31;
    }
    const int tx = threadIdx.x & 31, ty = threadIdx.x >> 5;
    const int r0 = rt * 32, c0 = ct * 32;
#pragma unroll
    for (int r = 0; r < 4; r++)
        t[ty + 8 * r][tx] = src[(size_t)(r0 + ty + 8 * r) * C + c0 + tx];
    __syncthreads();
#pragma unroll
    for (int r = 0; r < 4; r++)
        dst[(size_t)(c0 + ty + 8 * r) * R + r0 + tx] = t[tx][ty + 8 * r];
}

// ---------------------------------------------------------------------------
// R6 morpho7 with an MREP outer repeat around the staged k-loop (idempotent).
template <int JDIM, int KPER, int ZFOLD, int WSLICE>
__global__ __launch_bounds__(256, 2) void morphoR(const float* __restrict__ A,
                                                  const float* __restrict__ W,
                                                  float* __restrict__ P) {
    __shared__ float lA[64 * 64];    // [k][b] 16KB
    __shared__ float lW[64 * 64];    // [k][j] 16KB
    const int t  = threadIdx.x;
    const int tx = t & 15;           // b frag: b0 + tx*4 + {0..3}
    const int ty = t >> 4;           // j frag: j0 + ty*4 + {0..3}
    const int j0 = blockIdx.x * 64;
    const int b0 = blockIdx.y * 64;
    const int k0 = blockIdx.z * KPER;

    float acc[4][4];                 // [j][b], init 0 == relu fold
#pragma unroll
    for (int jj = 0; jj < 4; jj++)
#pragma unroll
        for (int i = 0; i < 4; i++) acc[jj][i] = 0.0f;

    const float4* lA4 = (const float4*)lA;
    const float4* lW4 = (const float4*)lW;

    for (int rep = 0; rep < MREP; rep++) {
        for (int ks = 0; ks < KPER; ks += 64) {
            if (ks | rep) __syncthreads();   // WAR before re-staging

            // ---- stage tiles: 1024 float4 each, 4/thread, coalesced ----
            const float4* A4 = (const float4*)(A + (size_t)(k0 + ks) * 512) + (b0 >> 2);
            const float4* W4 = (const float4*)(W + (size_t)(k0 + ks) * JDIM) + (j0 >> 2);
#pragma unroll
            for (int r = 0; r < 4; r++) {
                const int q   = t + 256 * r;
                const int row = q >> 4, col = q & 15;   // 16 f4 per 64-float row
                ((float4*)lA)[q] = A4[(size_t)row * 128 + col];
                const size_t woff = (size_t)row * (JDIM / 4) + col;
                float4 w = W4[woff];
                if (ZFOLD > 1) {
#pragma unroll
                    for (int z = 1; z < ZFOLD; z++)
                        w = fmax4(w, W4[woff + (size_t)z * WSLICE]);
                    w = fmax4(w, make_float4(0.f, 0.f, 0.f, 0.f));   // relu
                }
                ((float4*)lW)[q] = w;
            }
            __syncthreads();

            // ---- inner max-plus: 2 k's/iter; pk adds + v_max3 merges ----
#pragma unroll 8
            for (int kk = 0; kk < 64; kk += 2) {
                const float4 a0 = lA4[kk * 16 + tx];         // k,   b frag
                const float4 a1 = lA4[kk * 16 + 16 + tx];    // k+1, b frag
                const float4 w0 = lW4[kk * 16 + ty];         // k,   j frag
                const float4 w1 = lW4[kk * 16 + 16 + ty];    // k+1, j frag

                const f32x2 a0p0 = {a0.x, a0.y}, a0p1 = {a0.z, a0.w};
                const f32x2 a1p0 = {a1.x, a1.y}, a1p1 = {a1.z, a1.w};

#define UPDJ(JR, W0, W1)                                                    \
    {                                                                       \
        const f32x2 wa = {(W0), (W0)};                                      \
        const f32x2 wb = {(W1), (W1)};                                      \
        const f32x2 s0 = a0p0 + wa, t0 = a1p0 + wb;                         \
        const f32x2 s1 = a0p1 + wa, t1 = a1p1 + wb;                         \
        acc[JR][0] = fmaxf(fmaxf(acc[JR][0], s0.x), t0.x);                  \
        acc[JR][1] = fmaxf(fmaxf(acc[JR][1], s0.y), t0.y);                  \
        acc[JR][2] = fmaxf(fmaxf(acc[JR][2], s1.x), t1.x);                  \
        acc[JR][3] = fmaxf(fmaxf(acc[JR][3], s1.y), t1.y);                  \
    }
                UPDJ(0, w0.x, w1.x)
                UPDJ(1, w0.y, w1.y)
                UPDJ(2, w0.z, w1.z)
                UPDJ(3, w0.w, w1.w)
#undef UPDJ
            }
        }
    }

    // ---- store transposed partial: P[z][j][b], float4 over b (coalesced) ----
    float* Pp = P + (size_t)blockIdx.z * JDIM * 512;
#pragma unroll
    for (int jj = 0; jj < 4; jj++) {
        const float4 v = make_float4(acc[jj][0], acc[jj][1], acc[jj][2], acc[jj][3]);
        *(float4*)(Pp + (size_t)(j0 + ty * 4 + jj) * 512 + b0 + tx * 4) = v;
    }
}

// ---------------------------------------------------------------------------
// combineY: out[b][o] = max_z yp[z][b][o] — partials already relu-clamped
// (acc init 0) and already in [b][o] layout. Pure coalesced f4 max.
__global__ __launch_bounds__(256) void combineY2(const float* __restrict__ yp,
                                                 float* __restrict__ out) {
    const int i = blockIdx.x * 256 + threadIdx.x;   // float4 index
    const float4* p = (const float4*)yp;
    float4 m = p[i];
#pragma unroll
    for (int z = 1; z < 8; z++) m = fmax4(m, p[i + z * 65536]);  // 256K floats/4
    ((float4*)out)[i] = m;
}

// ---------------------------------------------------------------------------
extern "C" void kernel_launch(void* const* d_in, const int* in_sizes, int n_in,
                              void* d_out, int out_size, void* d_ws, size_t ws_size,
                              hipStream_t stream) {
    (void)in_sizes; (void)n_in; (void)out_size; (void)ws_size;
    const float* x  = (const float*)d_in[0];
    const float* W1 = (const float*)d_in[1];
    const float* W2 = (const float*)d_in[2];
    float* ws  = (float*)d_ws;
    float* out = (float*)d_out;

    // 1) K-major transposes of x, W1, W2
    transpose3<<<1280, 256, 0, stream>>>(x, W1, W2, ws);

    // 2) L1: hp[4][1024][512]; grid 16(j) x 8(b) x 4(z), KPER=128
    morphoR<1024, 128, 1, 1><<<dim3(16, 8, 4), 256, 0, stream>>>(
        ws + WS_XT, ws + WS_W1T, ws + WS_HP);

    // 3) L2 role-swapped: W-role = hp (ZFOLD=4 fused combine+relu),
    //    A-role = W2T. yp[8][512(b)][512(o)]; grid 8(b) x 8(o) x 8(z).
    morphoR<512, 128, 4, 131072><<<dim3(8, 8, 8), 256, 0, stream>>>(
        ws + WS_W2T, ws + WS_HP, ws + WS_YP);

    // 4) combine 8 partials -> d_out[b][o] (no transpose, pre-relu'd)
    combineY2<<<256, 256, 0, stream>>>(ws + WS_YP, out);
}

// Round 8
// 101.295 us; speedup vs baseline: 4.2295x; 1.9035x over previous
//
#include <hip/hip_runtime.h>

// MorphoMLP: y = relu(maxplus(relu(maxplus(x,W1)), W2)), fp32.
// B=512, IN=512, HID=1024, OUT=512.
// R10: R9 measurement round fixed the budget: fill 43.5us (harness, fixed) +
//      ~3.5us/dispatch gaps + transpose 4 + morphos ~31 + combine 2.
//      Morphos are LDS-pipe bound (12.6us vs 3.4us VALU floor, VALUBusy 58%).
//   - 128x128 tiles, 8x8 lo/hi frags: 1.0 B LDS/update (was 2.0).
//   - KPER=32, deep splitK (M1 z=16, M2 z=32): each block = ONE stage ->
//     ONE barrier -> 32-k compute burst. No k-loop barrier cycling (m233).
//     512 blocks (2/CU) both morphos.
//   - M2 keeps fused ZFOLD (now 16 slices) + relu in W-staging: pipeline
//     stays 4 dispatches (transpose3 -> M1 -> M2 -> combineY2).
//   - acc init 0 folds relu exactly: max_z max(0,p_z) == relu(max_z p_z).
// ws: xT 1MB | W1T 2MB | W2T 2MB | hp 32MB | yp 32MB = 69MB

#define WS_XT   0                           // [512][512]    x^T  [k][b]
#define WS_W1T  (512 * 512)                 // [512][1024]   W1^T [k][j]
#define WS_W2T  (WS_W1T + 512 * 1024)       // [1024][512]   W2^T [k2][o]
#define WS_HP   (WS_W2T + 1024 * 512)       // [16][1024][512] L1 partials [z][j][b]
#define WS_YP   (WS_HP + 16 * 1024 * 512)   // [32][512][512]  L2 partials [z][b][o]

typedef float f32x2 __attribute__((ext_vector_type(2)));

__device__ __forceinline__ float4 fmax4(float4 a, float4 b) {
    return make_float4(fmaxf(a.x, b.x), fmaxf(a.y, b.y),
                       fmaxf(a.z, b.z), fmaxf(a.w, b.w));
}

// ---------------------------------------------------------------------------
// Fused transpose of x (512x512), W1 (1024x512), W2 (512x1024) into ws.
__global__ __launch_bounds__(256) void transpose3(const float* __restrict__ x,
                                                  const float* __restrict__ W1,
                                                  const float* __restrict__ W2,
                                                  float* __restrict__ ws) {
    __shared__ float t[32][33];
    const int id = blockIdx.x;
    const float* src;
    float* dst;
    int R, C, rt, ct;
    if (id < 256) {
        src = x;  dst = ws + WS_XT;  R = 512;  C = 512;
        rt = id >> 4;          ct = id & 15;
    } else if (id < 768) {
        int b = id - 256;
        src = W1; dst = ws + WS_W1T; R = 1024; C = 512;
        rt = b >> 4;           ct = b & 15;
    } else {
        int b = id - 768;
        src = W2; dst = ws + WS_W2T; R = 512;  C = 1024;
        rt = b >> 5;           ct = b & 31;
    }
    const int tx = threadIdx.x & 31, ty = threadIdx.x >> 5;
    const int r0 = rt * 32, c0 = ct * 32;
#pragma unroll
    for (int r = 0; r < 4; r++)
        t[ty + 8 * r][tx] = src[(size_t)(r0 + ty + 8 * r) * C + c0 + tx];
    __syncthreads();
#pragma unroll
    for (int r = 0; r < 4; r++)
        dst[(size_t)(c0 + ty + 8 * r) * R + r0 + tx] = t[tx][ty + 8 * r];
}

// ---------------------------------------------------------------------------
// One-shot max-plus tile kernel: stage once, one barrier, 32-k burst.
// A-role: [K][512] K-major (b/o axis).  W-role: [K][JDIM] K-major (j axis).
// Block tile: 128 j x 128 b x 32 k. 256 threads, 8j x 8b lo/hi frags:
//   j = ty*4+{0..3} u 64+ty*4+{0..3},  b = tx*4+{0..3} u 64+tx*4+{0..3}.
// ZFOLD>1: W staging maxes ZFOLD slices (stride WSLICE f4) + relu — fuses
// the previous layer's combine. Stores partial P[bz][j][b], f4 over b.
template <int JDIM, int ZFOLD, int WSLICE>
__global__ __launch_bounds__(256, 2) void morpho8(const float* __restrict__ A,
                                                  const float* __restrict__ W,
                                                  float* __restrict__ P) {
    __shared__ float lA[32 * 128];   // [k][b] 16KB
    __shared__ float lW[32 * 128];   // [k][j] 16KB
    const int t  = threadIdx.x;
    const int tx = t & 15;
    const int ty = t >> 4;
    const int j0 = blockIdx.x * 128;
    const int b0 = blockIdx.y * 128;
    const int k0 = blockIdx.z * 32;

    // ---- stage both tiles: 1024 f4 each, 4/thread, coalesced ----
    const float4* A4 = (const float4*)(A + (size_t)k0 * 512) + (b0 >> 2);
    const float4* W4 = (const float4*)(W + (size_t)k0 * JDIM) + (j0 >> 2);
    for (int r = 0; r < 4; r++) {
        const int q   = t + 256 * r;
        const int row = q >> 5, col = q & 31;        // 32 f4 per 128-float row
        ((float4*)lA)[q] = A4[(size_t)row * 128 + col];
        const size_t woff = (size_t)row * (JDIM / 4) + col;
        float4 w = W4[woff];
        if (ZFOLD > 1) {
            for (int z = 1; z < ZFOLD; z++)
                w = fmax4(w, W4[woff + (size_t)z * WSLICE]);
            w = fmax4(w, make_float4(0.f, 0.f, 0.f, 0.f));   // relu
        }
        ((float4*)lW)[q] = w;
    }
    __syncthreads();                 // the ONLY barrier

    float acc[8][8];                 // [j][b], init 0 == relu fold
#pragma unroll
    for (int jj = 0; jj < 8; jj++)
#pragma unroll
        for (int i = 0; i < 8; i++) acc[jj][i] = 0.0f;

    const float4* lA4 = (const float4*)lA;
    const float4* lW4 = (const float4*)lW;

    // ---- inner max-plus: 2 k's/iter; pk adds (f32x2) + v_max3 merges ----
#pragma unroll 4
    for (int kk = 0; kk < 32; kk += 2) {
        const float4 aL0 = lA4[kk * 32 + tx];        // k,   b lo
        const float4 aH0 = lA4[kk * 32 + 16 + tx];   // k,   b hi
        const float4 aL1 = lA4[kk * 32 + 32 + tx];   // k+1, b lo
        const float4 aH1 = lA4[kk * 32 + 48 + tx];   // k+1, b hi
        const float4 wL0 = lW4[kk * 32 + ty];        // k,   j lo
        const float4 wH0 = lW4[kk * 32 + 16 + ty];   // k,   j hi
        const float4 wL1 = lW4[kk * 32 + 32 + ty];   // k+1, j lo
        const float4 wH1 = lW4[kk * 32 + 48 + ty];   // k+1, j hi

        const f32x2 aL0p0 = {aL0.x, aL0.y}, aL0p1 = {aL0.z, aL0.w};
        const f32x2 aH0p0 = {aH0.x, aH0.y}, aH0p1 = {aH0.z, aH0.w};
        const f32x2 aL1p0 = {aL1.x, aL1.y}, aL1p1 = {aL1.z, aL1.w};
        const f32x2 aH1p0 = {aH1.x, aH1.y}, aH1p1 = {aH1.z, aH1.w};

#define UPDJ(JR, W0, W1)                                                    \
    {                                                                       \
        const f32x2 wa = {(W0), (W0)};                                      \
        const f32x2 wb = {(W1), (W1)};                                      \
        const f32x2 s0 = aL0p0 + wa, u0 = aL1p0 + wb;                       \
        const f32x2 s1 = aL0p1 + wa, u1 = aL1p1 + wb;                       \
        const f32x2 s2 = aH0p0 + wa, u2 = aH1p0 + wb;                       \
        const f32x2 s3 = aH0p1 + wa, u3 = aH1p1 + wb;                       \
        acc[JR][0] = fmaxf(fmaxf(acc[JR][0], s0.x), u0.x);                  \
        acc[JR][1] = fmaxf(fmaxf(acc[JR][1], s0.y), u0.y);                  \
        acc[JR][2] = fmaxf(fmaxf(acc[JR][2], s1.x), u1.x);                  \
        acc[JR][3] = fmaxf(fmaxf(acc[JR][3], s1.y), u1.y);                  \
        acc[JR][4] = fmaxf(fmaxf(acc[JR][4], s2.x), u2.x);                  \
        acc[JR][5] = fmaxf(fmaxf(acc[JR][5], s2.y), u2.y);                  \
        acc[JR][6] = fmaxf(fmaxf(acc[JR][6], s3.x), u3.x);                  \
        acc[JR][7] = fmaxf(fmaxf(acc[JR][7], s3.y), u3.y);                  \
    }
        UPDJ(0, wL0.x, wL1.x)
        UPDJ(1, wL0.y, wL1.y)
        UPDJ(2, wL0.z, wL1.z)
        UPDJ(3, wL0.w, wL1.w)
        UPDJ(4, wH0.x, wH1.x)
        UPDJ(5, wH0.y, wH1.y)
        UPDJ(6, wH0.z, wH1.z)
        UPDJ(7, wH0.w, wH1.w)
#undef UPDJ
    }

    // ---- store partial: P[bz][j][b], 2 f4 per j-row, coalesced ----
    float* Pp = P + (size_t)blockIdx.z * JDIM * 512;
#pragma unroll
    for (int jj = 0; jj < 8; jj++) {
        const int jl = ((jj >> 2) << 6) + ty * 4 + (jj & 3);
        float* row = Pp + (size_t)(j0 + jl) * 512 + b0 + tx * 4;
        *(float4*)(row)      = make_float4(acc[jj][0], acc[jj][1], acc[jj][2], acc[jj][3]);
        *(float4*)(row + 64) = make_float4(acc[jj][4], acc[jj][5], acc[jj][6], acc[jj][7]);
    }
}

// ---------------------------------------------------------------------------
// combineY: out[b][o] = max_z yp[z][b][o] — partials already relu-clamped
// (acc init 0) and already [b][o]. Pure coalesced f4 max over 32 slices.
__global__ __launch_bounds__(256) void combineY2(const float* __restrict__ yp,
                                                 float* __restrict__ out) {
    const int i = blockIdx.x * 256 + threadIdx.x;   // f4 index over 256K floats
    const float4* p = (const float4*)yp;
    float4 m = p[i];
#pragma unroll
    for (int z = 1; z < 32; z++) m = fmax4(m, p[i + z * 65536]);  // 256K/4
    ((float4*)out)[i] = m;
}

// ---------------------------------------------------------------------------
extern "C" void kernel_launch(void* const* d_in, const int* in_sizes, int n_in,
                              void* d_out, int out_size, void* d_ws, size_t ws_size,
                              hipStream_t stream) {
    (void)in_sizes; (void)n_in; (void)out_size; (void)ws_size;
    const float* x  = (const float*)d_in[0];
    const float* W1 = (const float*)d_in[1];
    const float* W2 = (const float*)d_in[2];
    float* ws  = (float*)d_ws;
    float* out = (float*)d_out;

    // 1) K-major transposes of x, W1, W2
    transpose3<<<1280, 256, 0, stream>>>(x, W1, W2, ws);

    // 2) L1: hp[16][1024][512]; grid 8(j) x 4(b) x 16(z), KPER=32 one-shot
    morpho8<1024, 1, 1><<<dim3(8, 4, 16), 256, 0, stream>>>(
        ws + WS_XT, ws + WS_W1T, ws + WS_HP);

    // 3) L2 role-swapped: j-axis = b, b-axis = o. W-role = h (ZFOLD=16 fused
    //    combine+relu from hp slices, stride 1024*512/4 = 131072 f4);
    //    A-role = W2T. yp[32][512(b)][512(o)]; grid 4(b) x 4(o) x 32(z).
    morpho8<512, 16, 131072><<<dim3(4, 4, 32), 256, 0, stream>>>(
        ws + WS_W2T, ws + WS_HP, ws + WS_YP);

    // 4) combine 32 partials -> d_out[b][o] (no transpose, pre-relu'd)
    combineY2<<<256, 256, 0, stream>>>(ws + WS_YP, out);
}

// Round 9
// 95.258 us; speedup vs baseline: 4.4976x; 1.0634x over previous
//
#include <hip/hip_runtime.h>

// MorphoMLP: y = relu(maxplus(relu(maxplus(x,W1)), W2)), fp32.
// B=512, IN=512, HID=1024, OUT=512.
// R11: NT-formulation morpho — both operands K-CONTIGUOUS, inputs read RAW.
//   - out[j,b] = max_k(x[b][k]+W1[j][k]): x,W1,W2 staged row-major coalesced
//     -> transpose3 DELETED (was +4us work +3.5us gap +6MB traffic).
//   - LDS tiles [row][k] with XOR swizzle col^=(row>>2)&7 on BOTH write and
//     read (T2/G21): k-column reads across rows land on distinct bank-quads
//     (<=2-way alias = free).
//   - 128j x 64b x 64k one-shot blocks (stage once, ONE barrier, 16x4k burst),
//     8j x 4b frags: 683 upd/wave-read -> 7.7us/layer LDS floor (was 10.2).
//     k-contig frag: 2 pk_add + 2 v_max3 per 4 updates = 1.0 instr/update.
//   - z=8 (M1) / z=16 (M2) -> 512 blocks (2/CU, 48KB LDS) both layers.
//   - Partials stored [z][b][j]: combineH/combineY pure coalesced f4 maxes;
//     M2 consumes A2[b][k2] + W2[o][k2] naturally (NT again).
//   - acc init 0 folds relu exactly (max is order-exact; adds unreassociated
//     -> bit-exact, absmax 0).
// ws: hp 16MB | A2 2MB | yp 16MB = 34MB

#define WS_HP   0                            // [8][512][1024]  L1 partials [z][b][j]
#define WS_A2   (8 * 512 * 1024)             // [512][1024]     relu(h) [b][k2]
#define WS_YP   (WS_A2 + 512 * 1024)         // [16][512][512]  L2 partials [z][b][o]

typedef float f32x2 __attribute__((ext_vector_type(2)));

__device__ __forceinline__ float4 fmax4(float4 a, float4 b) {
    return make_float4(fmaxf(a.x, b.x), fmaxf(a.y, b.y),
                       fmaxf(a.z, b.z), fmaxf(a.w, b.w));
}

// ---------------------------------------------------------------------------
// NT max-plus tile kernel. A: [*][AROWF4*4] row-major (b-axis rows);
// W: [*][WROWF4*4] row-major (j-axis rows). Both k-contiguous.
// Block tile: 128 j x 64 b x 64 k, one-shot (stage, 1 barrier, burst).
// 256 thr: tx=t>>4 (4 b-rows: b0+tx*4+bi), ty=t&15 (8 j-rows: j0+ty*4+ji, +64).
// LDS [row][16 f4] with col^=(row>>2)&7 swizzle both sides.
// Stores partial P[bz][b][j] (f4 over j, coalesced via ty).
template <int AROWF4, int WROWF4, int OUTW>
__global__ __launch_bounds__(256, 2) void morphoNT(const float* __restrict__ A,
                                                   const float* __restrict__ Wm,
                                                   float* __restrict__ P) {
    __shared__ float lA[64 * 64];      // [b-row][k] swizzled, 16KB
    __shared__ float lW[128 * 64];     // [j-row][k] swizzled, 32KB
    const int t  = threadIdx.x;
    const int tx = t >> 4;             // b frag group
    const int ty = t & 15;             // j frag group
    const int j0 = blockIdx.x * 128;
    const int b0 = blockIdx.y * 64;
    const int k0f4 = blockIdx.z * 16;  // KPER=64 = 16 f4 per row

    const float4* A4 = (const float4*)A;
    const float4* W4 = (const float4*)Wm;
    float4* lA4 = (float4*)lA;
    float4* lW4 = (float4*)lW;

    // ---- stage A tile: 1024 f4 (4/thr), k-contig rows, swizzled col ----
#pragma unroll
    for (int s = 0; s < 4; s++) {
        const int q = t + 256 * s;
        const int r = q >> 4, c = q & 15;
        lA4[r * 16 + (c ^ ((r >> 2) & 7))] = A4[(size_t)(b0 + r) * AROWF4 + k0f4 + c];
    }
    // ---- stage W tile: 2048 f4 (8/thr) ----
#pragma unroll
    for (int s = 0; s < 8; s++) {
        const int q = t + 256 * s;
        const int r = q >> 4, c = q & 15;
        lW4[r * 16 + (c ^ ((r >> 2) & 7))] = W4[(size_t)(j0 + r) * WROWF4 + k0f4 + c];
    }
    __syncthreads();                   // the ONLY barrier

    float acc[4][8];                   // [bi][jr], init 0 == relu fold
#pragma unroll
    for (int bi = 0; bi < 4; bi++)
#pragma unroll
        for (int jr = 0; jr < 8; jr++) acc[bi][jr] = 0.0f;

    const int swA = tx & 7;            // ((tx*4+bi)>>2)&7, same for bi<4
    const int swW = ty & 7;            // ((ty*4+ji)>>2)&7 == ((64+ty*4+ji)>>2)&7
    const float4* pA  = lA4 + tx * 4 * 16;
    const float4* pWl = lW4 + ty * 4 * 16;
    const float4* pWh = lW4 + (64 + ty * 4) * 16;

    // ---- k burst: 16 iters x 4k; 12 b128 reads per 128 updates ----
#pragma unroll 4
    for (int c = 0; c < 16; c++) {
        const int cA = c ^ swA, cW = c ^ swW;
        float4 a[4], wl[4], wh[4];
#pragma unroll
        for (int bi = 0; bi < 4; bi++) a[bi] = pA[bi * 16 + cA];
#pragma unroll
        for (int ji = 0; ji < 4; ji++) {
            wl[ji] = pWl[ji * 16 + cW];
            wh[ji] = pWh[ji * 16 + cW];
        }
#pragma unroll
        for (int bi = 0; bi < 4; bi++) {
            const f32x2 alo = {a[bi].x, a[bi].y};
            const f32x2 ahi = {a[bi].z, a[bi].w};
#pragma unroll
            for (int jr = 0; jr < 8; jr++) {
                const float4 w = (jr < 4) ? wl[jr] : wh[jr - 4];
                const f32x2 s  = alo + (f32x2){w.x, w.y};   // pk_add
                const f32x2 u  = ahi + (f32x2){w.z, w.w};   // pk_add
                const float m  = fmaxf(fmaxf(s.x, s.y), u.x);        // v_max3
                acc[bi][jr]    = fmaxf(fmaxf(acc[bi][jr], m), u.y);  // v_max3
            }
        }
    }

    // ---- store partial: P[bz][b][j], f4 over j (coalesced: ty contiguous) ----
    float* Pp = P + (size_t)blockIdx.z * (512 * OUTW);
#pragma unroll
    for (int bi = 0; bi < 4; bi++) {
        float* row = Pp + (size_t)(b0 + tx * 4 + bi) * OUTW + j0 + ty * 4;
        *(float4*)(row)      = make_float4(acc[bi][0], acc[bi][1], acc[bi][2], acc[bi][3]);
        *(float4*)(row + 64) = make_float4(acc[bi][4], acc[bi][5], acc[bi][6], acc[bi][7]);
    }
}

// ---------------------------------------------------------------------------
// combineH: A2[b][k2] = relu(max_z hp[z][b][k2]). Coalesced f4, 8 slices.
// 512 blocks x 256 thr x 1 f4 = 512K floats.
__global__ __launch_bounds__(256) void combineH2(const float* __restrict__ hp,
                                                 float* __restrict__ A2) {
    const int i = blockIdx.x * 256 + threadIdx.x;    // f4 index
    const float4* p = (const float4*)hp;
    float4 m = p[i];
#pragma unroll
    for (int z = 1; z < 8; z++) m = fmax4(m, p[i + z * 131072]);  // 512K/4
    m = fmax4(m, make_float4(0.f, 0.f, 0.f, 0.f));
    ((float4*)A2)[i] = m;
}

// ---------------------------------------------------------------------------
// combineY: out[b][o] = max_z yp[z][b][o] (pre-relu'd). Coalesced, 16 slices.
// 256 blocks x 256 thr x 1 f4 = 256K floats.
__global__ __launch_bounds__(256) void combineY3(const float* __restrict__ yp,
                                                 float* __restrict__ out) {
    const int i = blockIdx.x * 256 + threadIdx.x;    // f4 index
    const float4* p = (const float4*)yp;
    float4 m = p[i];
#pragma unroll
    for (int z = 1; z < 16; z++) m = fmax4(m, p[i + z * 65536]);  // 256K/4
    ((float4*)out)[i] = m;
}

// ---------------------------------------------------------------------------
extern "C" void kernel_launch(void* const* d_in, const int* in_sizes, int n_in,
                              void* d_out, int out_size, void* d_ws, size_t ws_size,
                              hipStream_t stream) {
    (void)in_sizes; (void)n_in; (void)out_size; (void)ws_size;
    const float* x  = (const float*)d_in[0];   // [512][512]   b x k
    const float* W1 = (const float*)d_in[1];   // [1024][512]  j x k
    const float* W2 = (const float*)d_in[2];   // [512][1024]  o x k2
    float* ws  = (float*)d_ws;
    float* out = (float*)d_out;

    // 1) L1: hp[8][b][j]; grid 8(j) x 8(b) x 8(z), KPER=64, raw x/W1
    morphoNT<128, 128, 1024><<<dim3(8, 8, 8), 256, 0, stream>>>(
        x, W1, ws + WS_HP);

    // 2) combine 8 slices + relu -> A2[b][k2] (k2-contig for M2)
    combineH2<<<512, 256, 0, stream>>>(ws + WS_HP, ws + WS_A2);

    // 3) L2: yp[16][b][o]; grid 4(o) x 8(b) x 16(z), KPER=64, raw W2
    morphoNT<256, 256, 512><<<dim3(4, 8, 16), 256, 0, stream>>>(
        ws + WS_A2, W2, ws + WS_YP);

    // 4) combine 16 slices -> out[b][o]
    combineY3<<<256, 256, 0, stream>>>(ws + WS_YP, out);
}

// Round 10
// 95.140 us; speedup vs baseline: 4.5031x; 1.0012x over previous
//
#include <hip/hip_runtime.h>

// MorphoMLP: y = relu(maxplus(relu(maxplus(x,W1)), W2)), fp32.
// B=512, IN=512, HID=1024, OUT=512.
// R12: 4 -> 3 dispatches. Budget model (R4/R9 calibrated): ~40us harness fill
//      + ~6-7us/dispatch gap + ~30us kernel work. Only dispatch count and
//      kernel work remain addressable.
//   - combineH fused into M2's A-side staging (AFOLD=4 + relu), as R6 proved;
//     hp kept at z=4 (M1 KPER=128 via R6-proven 2-phase ks-loop) so fold
//     traffic is 32MB (R10's loss was 256MB at ZFOLD=16).
//   - NT formulation throughout (R11-proven): raw inputs, no transposes,
//     XOR swizzle col^=(row>>2)&7 on both LDS write and read.
//   - M1: 64j x 64b x 128k, 4x4 frag, z=4,  grid(16,8,4)=512 blocks, 32KB.
//   - M2: 128o x 64b x 64k, 8x4 frag,  z=16, grid(4,8,16)=512 blocks, 48KB.
//   - acc init 0 folds relu exactly; max order-exact -> absmax 0.
// ws: hp 8MB | yp 16MB = 24MB

#define WS_HP   0                            // [4][512][1024]  L1 partials [z][b][j]
#define WS_YP   (4 * 512 * 1024)             // [16][512][512]  L2 partials [z][b][o]

typedef float f32x2 __attribute__((ext_vector_type(2)));

__device__ __forceinline__ float4 fmax4(float4 a, float4 b) {
    return make_float4(fmaxf(a.x, b.x), fmaxf(a.y, b.y),
                       fmaxf(a.z, b.z), fmaxf(a.w, b.w));
}

// ---------------------------------------------------------------------------
// NT max-plus tile kernel, parameterized (R11 inner loop verbatim).
// A: [*][AROWF4*4] row-major (b-axis rows); W: [*][WROWF4*4] row-major
// (j/o-axis rows). Both k-contiguous. Block tile: JTILE j x 64 b x KPER k,
// staged in 64-k phases (KPER/64 phases, barrier-cycled as R6).
// 256 thr: tx=t>>4 -> 4 b-rows (b0+tx*4+bi); ty=t&15 -> JTILE/16 j-rows.
// LDS [row][16 f4], swizzle col^=(row>>2)&7 both sides.
// AFOLD>1: A staging maxes AFOLD slices (stride ASLICEF4 f4) + relu — fuses
// the previous layer's combine. Stores partial P[bz][b][j] (f4 over j).
template <int JTILE, int KPER, int AROWF4, int WROWF4, int OUTW,
          int AFOLD, int ASLICEF4>
__global__ __launch_bounds__(256, 2) void morphoNT2(const float* __restrict__ A,
                                                    const float* __restrict__ Wm,
                                                    float* __restrict__ P) {
    constexpr int JROWS = JTILE / 16;          // 4 or 8 j-rows per thread
    __shared__ float lA[64 * 64];              // [b-row][64k] swizzled, 16KB
    __shared__ float lW[JTILE * 64];           // [j-row][64k] swizzled
    const int t  = threadIdx.x;
    const int tx = t >> 4;
    const int ty = t & 15;
    const int j0 = blockIdx.x * JTILE;
    const int b0 = blockIdx.y * 64;
    const int kbase = blockIdx.z * (KPER / 4); // f4 units

    const float4* A4 = (const float4*)A;
    const float4* W4 = (const float4*)Wm;
    float4* lA4 = (float4*)lA;
    float4* lW4 = (float4*)lW;

    float acc[4][JROWS];                       // [bi][jr], init 0 == relu fold
#pragma unroll
    for (int bi = 0; bi < 4; bi++)
#pragma unroll
        for (int jr = 0; jr < JROWS; jr++) acc[bi][jr] = 0.0f;

    const int swA = tx & 7;                    // ((tx*4+bi)>>2)&7, bi<4
    const int swW = ty & 7;                    // same for ty*4+ji and 64+ty*4+ji

    for (int ph = 0; ph < KPER / 64; ph++) {
        if (ph) __syncthreads();               // WAR before re-staging
        const int kf4 = kbase + ph * 16;

        // ---- stage A tile: 1024 f4 (4/thr), optional AFOLD combine ----
#pragma unroll
        for (int s = 0; s < 4; s++) {
            const int q = t + 256 * s;
            const int r = q >> 4, c = q & 15;
            const size_t off = (size_t)(b0 + r) * AROWF4 + kf4 + c;
            float4 v = A4[off];
            if (AFOLD > 1) {
#pragma unroll
                for (int z = 1; z < AFOLD; z++)
                    v = fmax4(v, A4[off + (size_t)z * ASLICEF4]);
                v = fmax4(v, make_float4(0.f, 0.f, 0.f, 0.f));   // relu
            }
            lA4[r * 16 + (c ^ ((r >> 2) & 7))] = v;
        }
        // ---- stage W tile: JTILE*16 f4 (JROWS/thr... JTILE/16 per thread) ----
#pragma unroll
        for (int s = 0; s < JTILE / 16; s++) {
            const int q = t + 256 * s;
            const int r = q >> 4, c = q & 15;
            lW4[r * 16 + (c ^ ((r >> 2) & 7))] =
                W4[(size_t)(j0 + r) * WROWF4 + kf4 + c];
        }
        __syncthreads();

        const float4* pA  = lA4 + tx * 4 * 16;
        const float4* pWl = lW4 + ty * 4 * 16;
        const float4* pWh = lW4 + (64 + ty * 4) * 16;   // JROWS==8 only

        // ---- k burst: 16 iters x 4k; pk_add + v_max3, 1 instr/update ----
#pragma unroll 4
        for (int c = 0; c < 16; c++) {
            const int cA = c ^ swA, cW = c ^ swW;
            float4 a[4];
#pragma unroll
            for (int bi = 0; bi < 4; bi++) a[bi] = pA[bi * 16 + cA];
            float4 w[JROWS];
#pragma unroll
            for (int ji = 0; ji < 4; ji++) w[ji] = pWl[ji * 16 + cW];
            if (JROWS == 8) {
#pragma unroll
                for (int ji = 0; ji < 4; ji++) w[4 + ji] = pWh[ji * 16 + cW];
            }
#pragma unroll
            for (int bi = 0; bi < 4; bi++) {
                const f32x2 alo = {a[bi].x, a[bi].y};
                const f32x2 ahi = {a[bi].z, a[bi].w};
#pragma unroll
                for (int jr = 0; jr < JROWS; jr++) {
                    const f32x2 s = alo + (f32x2){w[jr].x, w[jr].y};  // pk_add
                    const f32x2 u = ahi + (f32x2){w[jr].z, w[jr].w};  // pk_add
                    const float m = fmaxf(fmaxf(s.x, s.y), u.x);      // v_max3
                    acc[bi][jr]   = fmaxf(fmaxf(acc[bi][jr], m), u.y);// v_max3
                }
            }
        }
    }

    // ---- store partial: P[bz][b][j], f4 over j (coalesced via ty) ----
    float* Pp = P + (size_t)blockIdx.z * (512 * OUTW);
#pragma unroll
    for (int bi = 0; bi < 4; bi++) {
        float* row = Pp + (size_t)(b0 + tx * 4 + bi) * OUTW + j0 + ty * 4;
        *(float4*)(row) = make_float4(acc[bi][0], acc[bi][1], acc[bi][2], acc[bi][3]);
        if (JROWS == 8)
            *(float4*)(row + 64) =
                make_float4(acc[bi][4], acc[bi][5], acc[bi][6], acc[bi][7]);
    }
}

// ---------------------------------------------------------------------------
// combineY: out[b][o] = max_z yp[z][b][o] (pre-relu'd). Coalesced, 16 slices.
// 256 blocks x 256 thr x 1 f4 = 256K floats.
__global__ __launch_bounds__(256) void combineY3(const float* __restrict__ yp,
                                                 float* __restrict__ out) {
    const int i = blockIdx.x * 256 + threadIdx.x;    // f4 index
    const float4* p = (const float4*)yp;
    float4 m = p[i];
#pragma unroll
    for (int z = 1; z < 16; z++) m = fmax4(m, p[i + z * 65536]);  // 256K/4
    ((float4*)out)[i] = m;
}

// ---------------------------------------------------------------------------
extern "C" void kernel_launch(void* const* d_in, const int* in_sizes, int n_in,
                              void* d_out, int out_size, void* d_ws, size_t ws_size,
                              hipStream_t stream) {
    (void)in_sizes; (void)n_in; (void)out_size; (void)ws_size;
    const float* x  = (const float*)d_in[0];   // [512][512]   b x k
    const float* W1 = (const float*)d_in[1];   // [1024][512]  j x k
    const float* W2 = (const float*)d_in[2];   // [512][1024]  o x k2
    float* ws  = (float*)d_ws;
    float* out = (float*)d_out;

    // 1) L1: hp[4][b][j]; JTILE=64, KPER=128 (2-phase), z=4.
    //    grid 16(j) x 8(b) x 4(z) = 512 blocks, 32KB LDS.
    morphoNT2<64, 128, 128, 128, 1024, 1, 1>
        <<<dim3(16, 8, 4), 256, 0, stream>>>(x, W1, ws + WS_HP);

    // 2) L2: yp[16][b][o]; JTILE=128, KPER=64 (one-shot), z=16.
    //    A-side = hp with AFOLD=4 fused combine+relu (slice stride
    //    512*1024/4 = 131072 f4); W-side = raw W2.
    //    grid 4(o) x 8(b) x 16(z) = 512 blocks, 48KB LDS.
    morphoNT2<128, 64, 256, 256, 512, 4, 131072>
        <<<dim3(4, 8, 16), 256, 0, stream>>>(ws + WS_HP, W2, ws + WS_YP);

    // 3) combine 16 slices -> out[b][o]
    combineY3<<<256, 256, 0, stream>>>(ws + WS_YP, out);
}

// Round 11
// 91.230 us; speedup vs baseline: 4.6961x; 1.0429x over previous
//
#include <hip/hip_runtime.h>

// MorphoMLP: y = relu(maxplus(relu(maxplus(x,W1)), W2)), fp32.
// B=512, IN=512, HID=1024, OUT=512.
// R13: minimize CROSS-DISPATCH-BOUNDARY bytes (per-XCD L2 non-coherence =>
//      every boundary is writeback+invalidate; consumer reads are cold).
//      R12 moved 74MB across boundaries; this moves 39MB.
//   - M1: R12 verbatim (NT, JTILE=64, KPER=128 2-phase, z=4, hp 8MB).
//   - combineH restored: hp(8MB) -> A2(2MB) once, instead of M2 AFOLD
//     re-reading hp 8x (32MB cold).
//   - M2: NT, JTILE=64, KPER=128 2-phase, z=8 -> yp 8MB (was 16MB).
//   - combineY: 8 slices -> out[b][o].
//   - NT formulation (R11): raw inputs, no transposes; LDS [row][16f4] with
//     col^=(row>>2)&7 XOR swizzle on both write and read.
//   - acc init 0 folds relu exactly; max order-exact -> absmax 0.
// ws: hp 8MB | A2 2MB | yp 8MB = 18MB

#define WS_HP   0                            // [4][512][1024]  L1 partials [z][b][j]
#define WS_A2   (4 * 512 * 1024)             // [512][1024]     relu(h) [b][k2]
#define WS_YP   (WS_A2 + 512 * 1024)         // [8][512][512]   L2 partials [z][b][o]

typedef float f32x2 __attribute__((ext_vector_type(2)));

__device__ __forceinline__ float4 fmax4(float4 a, float4 b) {
    return make_float4(fmaxf(a.x, b.x), fmaxf(a.y, b.y),
                       fmaxf(a.z, b.z), fmaxf(a.w, b.w));
}

// ---------------------------------------------------------------------------
// NT max-plus tile kernel (R12 morphoNT2, AFOLD removed).
// A: [*][AROWF4*4] row-major (b-axis rows); W: [*][WROWF4*4] row-major
// (j/o-axis rows). Both k-contiguous. Block tile: JTILE j x 64 b x KPER k,
// staged in 64-k phases. 256 thr: tx=t>>4 -> 4 b-rows; ty=t&15 -> JTILE/16
// j-rows. LDS [row][16 f4], swizzle col^=(row>>2)&7 both sides.
// Stores partial P[bz][b][j] (f4 over j, coalesced via ty).
template <int JTILE, int KPER, int AROWF4, int WROWF4, int OUTW>
__global__ __launch_bounds__(256, 2) void morphoNT3(const float* __restrict__ A,
                                                    const float* __restrict__ Wm,
                                                    float* __restrict__ P) {
    constexpr int JROWS = JTILE / 16;          // 4 j-rows per thread here
    __shared__ float lA[64 * 64];              // [b-row][64k] swizzled, 16KB
    __shared__ float lW[JTILE * 64];           // [j-row][64k] swizzled
    const int t  = threadIdx.x;
    const int tx = t >> 4;
    const int ty = t & 15;
    const int j0 = blockIdx.x * JTILE;
    const int b0 = blockIdx.y * 64;
    const int kbase = blockIdx.z * (KPER / 4); // f4 units

    const float4* A4 = (const float4*)A;
    const float4* W4 = (const float4*)Wm;
    float4* lA4 = (float4*)lA;
    float4* lW4 = (float4*)lW;

    float acc[4][JROWS];                       // [bi][jr], init 0 == relu fold
#pragma unroll
    for (int bi = 0; bi < 4; bi++)
#pragma unroll
        for (int jr = 0; jr < JROWS; jr++) acc[bi][jr] = 0.0f;

    const int swA = tx & 7;                    // ((tx*4+bi)>>2)&7, bi<4
    const int swW = ty & 7;                    // ((ty*4+ji)>>2)&7

    for (int ph = 0; ph < KPER / 64; ph++) {
        if (ph) __syncthreads();               // WAR before re-staging
        const int kf4 = kbase + ph * 16;

        // ---- stage A tile: 1024 f4 (4/thr), coalesced, swizzled ----
#pragma unroll
        for (int s = 0; s < 4; s++) {
            const int q = t + 256 * s;
            const int r = q >> 4, c = q & 15;
            lA4[r * 16 + (c ^ ((r >> 2) & 7))] =
                A4[(size_t)(b0 + r) * AROWF4 + kf4 + c];
        }
        // ---- stage W tile: JTILE*16 f4 ----
#pragma unroll
        for (int s = 0; s < JTILE / 16; s++) {
            const int q = t + 256 * s;
            const int r = q >> 4, c = q & 15;
            lW4[r * 16 + (c ^ ((r >> 2) & 7))] =
                W4[(size_t)(j0 + r) * WROWF4 + kf4 + c];
        }
        __syncthreads();

        const float4* pA  = lA4 + tx * 4 * 16;
        const float4* pWl = lW4 + ty * 4 * 16;

        // ---- k burst: 16 iters x 4k; pk_add + v_max3 ----
#pragma unroll 4
        for (int c = 0; c < 16; c++) {
            const int cA = c ^ swA, cW = c ^ swW;
            float4 a[4];
#pragma unroll
            for (int bi = 0; bi < 4; bi++) a[bi] = pA[bi * 16 + cA];
            float4 w[JROWS];
#pragma unroll
            for (int ji = 0; ji < JROWS; ji++) w[ji] = pWl[ji * 16 + cW];
#pragma unroll
            for (int bi = 0; bi < 4; bi++) {
                const f32x2 alo = {a[bi].x, a[bi].y};
                const f32x2 ahi = {a[bi].z, a[bi].w};
#pragma unroll
                for (int jr = 0; jr < JROWS; jr++) {
                    const f32x2 s = alo + (f32x2){w[jr].x, w[jr].y};  // pk_add
                    const f32x2 u = ahi + (f32x2){w[jr].z, w[jr].w};  // pk_add
                    const float m = fmaxf(fmaxf(s.x, s.y), u.x);      // v_max3
                    acc[bi][jr]   = fmaxf(fmaxf(acc[bi][jr], m), u.y);// v_max3
                }
            }
        }
    }

    // ---- store partial: P[bz][b][j], f4 over j (coalesced via ty) ----
    float* Pp = P + (size_t)blockIdx.z * (512 * OUTW);
#pragma unroll
    for (int bi = 0; bi < 4; bi++) {
        float* row = Pp + (size_t)(b0 + tx * 4 + bi) * OUTW + j0 + ty * 4;
        *(float4*)(row) = make_float4(acc[bi][0], acc[bi][1], acc[bi][2], acc[bi][3]);
    }
}

// ---------------------------------------------------------------------------
// combineH: A2[b][k2] = relu(max_z hp[z][b][k2]). Coalesced f4, 4 slices.
// 512 blocks x 256 thr x 1 f4 = 512K floats.
__global__ __launch_bounds__(256) void combineH3(const float* __restrict__ hp,
                                                 float* __restrict__ A2) {
    const int i = blockIdx.x * 256 + threadIdx.x;    // f4 index
    const float4* p = (const float4*)hp;
    float4 m = p[i];
#pragma unroll
    for (int z = 1; z < 4; z++) m = fmax4(m, p[i + z * 131072]);  // 512K/4
    m = fmax4(m, make_float4(0.f, 0.f, 0.f, 0.f));
    ((float4*)A2)[i] = m;
}

// ---------------------------------------------------------------------------
// combineY: out[b][o] = max_z yp[z][b][o] (pre-relu'd). Coalesced, 8 slices.
// 256 blocks x 256 thr x 1 f4 = 256K floats.
__global__ __launch_bounds__(256) void combineY4(const float* __restrict__ yp,
                                                 float* __restrict__ out) {
    const int i = blockIdx.x * 256 + threadIdx.x;    // f4 index
    const float4* p = (const float4*)yp;
    float4 m = p[i];
#pragma unroll
    for (int z = 1; z < 8; z++) m = fmax4(m, p[i + z * 65536]);  // 256K/4
    ((float4*)out)[i] = m;
}

// ---------------------------------------------------------------------------
extern "C" void kernel_launch(void* const* d_in, const int* in_sizes, int n_in,
                              void* d_out, int out_size, void* d_ws, size_t ws_size,
                              hipStream_t stream) {
    (void)in_sizes; (void)n_in; (void)out_size; (void)ws_size;
    const float* x  = (const float*)d_in[0];   // [512][512]   b x k
    const float* W1 = (const float*)d_in[1];   // [1024][512]  j x k
    const float* W2 = (const float*)d_in[2];   // [512][1024]  o x k2
    float* ws  = (float*)d_ws;
    float* out = (float*)d_out;

    // 1) L1: hp[4][b][j]; JTILE=64, KPER=128 (2-phase), z=4.
    //    grid 16(j) x 8(b) x 4(z) = 512 blocks, 32KB LDS.
    morphoNT3<64, 128, 128, 128, 1024>
        <<<dim3(16, 8, 4), 256, 0, stream>>>(x, W1, ws + WS_HP);

    // 2) combine 4 slices + relu -> A2[b][k2] (2MB; k2-contig for M2)
    combineH3<<<512, 256, 0, stream>>>(ws + WS_HP, ws + WS_A2);

    // 3) L2: yp[8][b][o]; JTILE=64, KPER=128 (2-phase), z=8.
    //    grid 8(o) x 8(b) x 8(z) = 512 blocks, 32KB LDS.
    morphoNT3<64, 128, 256, 256, 512>
        <<<dim3(8, 8, 8), 256, 0, stream>>>(ws + WS_A2, W2, ws + WS_YP);

    // 4) combine 8 slices -> out[b][o]
    combineY4<<<256, 256, 0, stream>>>(ws + WS_YP, out);
}